// Round 12
// baseline (519.482 us; speedup 1.0000x reference)
//
#include <hip/hip_runtime.h>
#include <hip/hip_fp16.h>
#include <math.h>

#define DEPTH 6
#define HEADS 8
#define BB    2
#define NN    128
#define EE    160
#define NF    127
#define DIMM  128
#define INNER 512
#define NNODE 256
#define GRID  256

__device__ __forceinline__ void fma4h(float4& acc, float a, float2 raw) {
    const __half2* hp = (const __half2*)&raw;
    float2 lo = __half22float2(hp[0]);
    float2 hi = __half22float2(hp[1]);
    acc.x += a * lo.x; acc.y += a * lo.y; acc.z += a * hi.x; acc.w += a * hi.y;
}

__device__ __forceinline__ void gload16(const void* g, void* l) {
    __builtin_amdgcn_global_load_lds((const __attribute__((address_space(1))) void*)g,
                                     (__attribute__((address_space(3))) void*)l,
                                     16, 0, 0);
}

// Stage one 32 KB chunk linearly into LDS (512 threads x 4 DMA each).
__device__ __forceinline__ void stage32kB(const void* g, void* lds) {
    int t = threadIdx.x;
    const char* gt = (const char*)g + t * 16;
    char* lb = (char*)lds + (t >> 6) * 1024;
#pragma unroll
    for (int r = 0; r < 4; r++) gload16(gt + r * 8192, lb + r * 8192);
}

__device__ __forceinline__ float block_reduce_sum_8w(float val, float* sbuf) {
#pragma unroll
    for (int off = 32; off > 0; off >>= 1) val += __shfl_xor(val, off, 64);
    int wave = threadIdx.x >> 6;
    if ((threadIdx.x & 63) == 0) sbuf[wave] = val;
    __syncthreads();
    float r = sbuf[0] + sbuf[1] + sbuf[2] + sbuf[3] + sbuf[4] + sbuf[5] + sbuf[6] + sbuf[7];
    __syncthreads();
    return r;
}

// One-shot grid barrier: slot used once per launch; zeroed by k_init.
__device__ __forceinline__ void gridbar(int* bar, int idx) {
    __syncthreads();
    if (threadIdx.x == 0) {
        __hip_atomic_fetch_add(&bar[idx], 1, __ATOMIC_RELEASE, __HIP_MEMORY_SCOPE_AGENT);
        while (__hip_atomic_load(&bar[idx], __ATOMIC_ACQUIRE, __HIP_MEMORY_SCOPE_AGENT) < GRID)
            __builtin_amdgcn_s_sleep(2);
    }
    __syncthreads();
}

__global__ void k_init(int* bar) {
    if (threadIdx.x < 16) bar[threadIdx.x] = 0;
}

__global__ __launch_bounds__(512, 2) void k_mega(
        const int* indices, const float* coords, const int* bonds, const float* noise,
        const float* atom_emb, const float* ln1_g, const float* ln1_b,
        const float* Wq, const float* bq, const float* Wkv, const float* bkv,
        const float* We, const float* be, const float* Wo, const float* bo,
        const float* Wg1, const float* ln2_g, const float* ln2_b,
        const float* W1, const float* b1, const float* W2, const float* b2,
        const float* Wg2, const float* Wlin, const float* blin,
        int* bar, float* nodes, float* xn, float* qb,
        __half* hk, __half* hv,
        __half* hWq, __half* hWkv, __half* hWo, __half* hW1, __half* hW2,
        float* out) {
    int bx = blockIdx.x;
    int t  = threadIdx.x;

    __shared__ float scoord[3 * NN];
    __shared__ float sedge[3 * NN];
    __shared__ int   sadj[NN];
    __shared__ float s_o[4 * INNER];
    __shared__ float s_l[4 * HEADS];
    __shared__ float s_ao[INNER];
    __shared__ float s_h[INNER];
    __shared__ float s_xn[128];
    __shared__ float s_red[8];
    __shared__ float s_part[4096];
    __shared__ float s_stage[16384];
    float* buf0 = s_stage;
    float* buf1 = s_stage + 8192;
    float* s_wA = s_stage;          // stage A aliases: 8192 floats (32 KB weights)
    float* s_xA = s_stage + 8192;   // 2048 floats (16-node x-tile)

    // ================= CVT stage: fp32 weights -> fp16 in ws =================
#pragma unroll
    for (int i = 0; i < 5; i++) {
        int local = i * 512 + t;
        if (local < 2304) {
            int g = bx * 2304 + local;   // float4 index, 0..589823
            const float4* src; __half* dst; int off;
            if (g < 98304)       { src = (const float4*)Wq;  dst = hWq;  off = g; }
            else if (g < 294912) { src = (const float4*)Wkv; dst = hWkv; off = g - 98304; }
            else if (g < 393216) { src = (const float4*)Wo;  dst = hWo;  off = g - 294912; }
            else if (g < 491520) { src = (const float4*)W1;  dst = hW1;  off = g - 393216; }
            else                 { src = (const float4*)W2;  dst = hW2;  off = g - 491520; }
            float4 v = src[off];
            __half2* d2 = (__half2*)(dst + (size_t)off * 4);
            d2[0] = __floats2half2_rn(v.x, v.y);
            d2[1] = __floats2half2_rn(v.z, v.w);
        }
    }
    // node init + LN1(layer0) for node bx
    {
        int d = t & 127;
        bool own = (t < 128);
        float nd = 0.0f;
        if (own) {
            int idx = indices[bx];
            nd = (d < NF) ? atom_emb[idx * NF + d] : noise[0];
            nodes[bx * DIMM + d] = nd;
        }
        float m   = block_reduce_sum_8w(own ? nd : 0.0f, s_red) * (1.0f / 128.0f);
        float df  = nd - m;
        float var = block_reduce_sum_8w(own ? df * df : 0.0f, s_red) * (1.0f / 128.0f);
        if (own) xn[bx * DIMM + d] = df * rsqrtf(var + 1e-5f) * ln1_g[d] + ln1_b[d];
    }
    gridbar(bar, 0);

    for (int l = 0; l < DEPTH; l++) {
        // ================= Stage A: tiled QKV GEMM =================
        if (bx < 192) {
            int nt = bx & 15;     // node tile: nodes nt*16..+15
            int ct = bx >> 4;     // col tile: 0..11 (128 cols each of [q|k|v])
            ((float4*)s_xA)[t] = ((const float4*)(xn + nt * 2048))[t];
            const __half* wsrc; int rowstr, colbase;
            if (ct < 4) { wsrc = hWq  + (size_t)l * DIMM * INNER;     rowstr = 512;  colbase = ct * 128; }
            else        { wsrc = hWkv + (size_t)l * DIMM * 2 * INNER; rowstr = 1024; colbase = (ct - 4) * 128; }
#pragma unroll
            for (int p = 0; p < 4; p++) {
                int idx = p * 512 + t;      // float4 units (8 halves)
                int r = idx >> 4, off = idx & 15;
                ((float4*)s_wA)[idx] = *(const float4*)(wsrc + (size_t)r * rowstr + colbase + off * 8);
            }
            __syncthreads();
            int n = t >> 5, cq = t & 31;
            float4 acc = {0, 0, 0, 0};
            const float*  xr = s_xA + n * 128;
            const float2* wr = (const float2*)s_wA;
#pragma unroll 8
            for (int k = 0; k < 128; k++) fma4h(acc, xr[k], wr[k * 32 + cq]);
            int node = nt * 16 + n;
            if (ct < 4) {
                float4 b4 = ((const float4*)(bq + (size_t)l * INNER))[ct * 32 + cq];
                acc.x += b4.x; acc.y += b4.y; acc.z += b4.z; acc.w += b4.w;
                ((float4*)(qb + (size_t)node * INNER))[ct * 32 + cq] = acc;
            } else {
                int kv = (ct < 8) ? 0 : 1;
                int cql = (ct - 4 - kv * 4) * 32 + cq;
                float4 b4 = ((const float4*)(bkv + (size_t)l * 2 * INNER))[kv * 128 + cql];
                acc.x += b4.x; acc.y += b4.y; acc.z += b4.z; acc.w += b4.w;
                float2 pack;
                ((__half2*)&pack)[0] = __floats2half2_rn(acc.x, acc.y);
                ((__half2*)&pack)[1] = __floats2half2_rn(acc.z, acc.w);
                __half* dst = kv ? hv : hk;
                ((float2*)(dst + (size_t)node * INNER))[cql] = pack;
            }
        }
        gridbar(bar, 1 + 2 * l);

        // ================= Stage B: per-node attention + post =================
        {
            int bn = bx;
            int b = bn >> 7, i = bn & 127;
            int d = t & 127;
            bool own = (t < 128);
            const __half* WoL = hWo + (size_t)l * INNER * DIMM;

            int jg = t >> 7, c = t & 127, h = c >> 4;
            const float4* qR  = (const float4*)(qb + (size_t)bn * INNER);
            const float4* WeR = (const float4*)(We + (size_t)l * 3 * INNER);
            float4 qv  = qR[c];
            float4 we0 = WeR[c], we1 = WeR[128 + c], we2 = WeR[256 + c];
            float4 bev = ((const float4*)(be + (size_t)l * INNER))[c];
            float res = own ? nodes[bn * DIMM + d] : 0.0f;

            if (t < 3 * NN) scoord[t] = coords[b * 3 * NN + t];
            if (t < NN) sadj[t] = 0;
            __syncthreads();
            if (t < EE) {
                int e0 = bonds[2 * t], e1 = bonds[2 * t + 1];
                if (e0 == i) sadj[e1] = 1;
                if (e1 == i) sadj[e0] = 1;
            }
            __syncthreads();
            if (t < NN) {
                int j = t;
                float msk = sadj[j] ? 1.0f : 0.0f;
                sedge[3 * j + 0] = msk * (scoord[3 * i + 0] - scoord[3 * j + 0]);
                sedge[3 * j + 1] = msk * (scoord[3 * i + 1] - scoord[3 * j + 1]);
                sedge[3 * j + 2] = msk * (scoord[3 * i + 2] - scoord[3 * j + 2]);
            }
            __syncthreads();

            stage32kB(WoL, buf0);   // overlap first Wo chunk with j-loop

            const float2* kR2 = (const float2*)(hk + (size_t)b * NN * INNER);
            const float2* vR2 = (const float2*)(hv + (size_t)b * NN * INNER);
            float l_run = 0.0f;
            float4 o_run = {0, 0, 0, 0};
            int j0 = jg * 32;
#pragma unroll
            for (int base = 0; base < 32; base += 8) {
                float2 kraw[8], vraw[8];
#pragma unroll
                for (int p = 0; p < 8; p++) {
                    int j = j0 + base + p;
                    kraw[p] = kR2[j * 128 + c];
                    vraw[p] = vR2[j * 128 + c];
                }
#pragma unroll
                for (int p = 0; p < 8; p++) {
                    int j = j0 + base + p;
                    float ex = sedge[3 * j], ey = sedge[3 * j + 1], ez = sedge[3 * j + 2];
                    float4 e;
                    e.x = bev.x + ex * we0.x + ey * we1.x + ez * we2.x;
                    e.y = bev.y + ex * we0.y + ey * we1.y + ez * we2.y;
                    e.z = bev.z + ex * we0.z + ey * we1.z + ez * we2.z;
                    e.w = bev.w + ex * we0.w + ey * we1.w + ez * we2.w;
                    const __half2* kh = (const __half2*)&kraw[p];
                    float2 k01 = __half22float2(kh[0]), k23 = __half22float2(kh[1]);
                    float s = (qv.x * (k01.x + e.x) + qv.y * (k01.y + e.y))
                            + (qv.z * (k23.x + e.z) + qv.w * (k23.y + e.w));
                    s += __shfl_xor(s, 1, 64);
                    s += __shfl_xor(s, 2, 64);
                    s += __shfl_xor(s, 4, 64);
                    s += __shfl_xor(s, 8, 64);
                    float pp = __expf(s * 0.125f);
                    const __half2* vh = (const __half2*)&vraw[p];
                    float2 v01 = __half22float2(vh[0]), v23 = __half22float2(vh[1]);
                    l_run += pp;
                    o_run.x += pp * (v01.x + e.x);
                    o_run.y += pp * (v01.y + e.y);
                    o_run.z += pp * (v23.x + e.z);
                    o_run.w += pp * (v23.y + e.w);
                }
            }
            ((float4*)(s_o + jg * INNER))[c] = o_run;
            if ((c & 15) == 0) s_l[jg * HEADS + h] = l_run;
            __syncthreads();
            if (jg == 0) {
                float4 o = o_run;
                float lsum = l_run;
#pragma unroll
                for (int g = 1; g < 4; g++) {
                    float4 og = ((float4*)(s_o + g * INNER))[c];
                    o.x += og.x; o.y += og.y; o.z += og.z; o.w += og.w;
                    lsum += s_l[g * HEADS + h];
                }
                float inv = 1.0f / lsum;
                float4 rr; rr.x = o.x * inv; rr.y = o.y * inv; rr.z = o.z * inv; rr.w = o.w * inv;
                ((float4*)s_ao)[c] = rr;
            }
            __syncthreads();

            // Wo fp16: 4 chunks x 128 rows
            int c5 = t & 31, kg16 = t >> 5;
            {
                float4 acw = {0, 0, 0, 0};
                for (int cc = 0; cc < 4; cc++) {
                    __syncthreads();
                    if (cc < 3) stage32kB(WoL + (cc + 1) * 16384, (cc & 1) ? buf0 : buf1);
                    const float2* w2 = (const float2*)((cc & 1) ? buf1 : buf0);
#pragma unroll
                    for (int rr = 0; rr < 8; rr++) {
                        int row = kg16 * 8 + rr;
                        fma4h(acw, s_ao[cc * 128 + row], w2[row * 32 + c5]);
                    }
                }
                ((float4*)(s_part + kg16 * 128))[c5] = acw;
            }
            __syncthreads();
            float x = 0.0f;
            if (own) {
                x = bo[l * DIMM + d];
#pragma unroll
                for (int g = 0; g < 16; g++) x += s_part[g * 128 + d];
            }

            const float* Wg1_l = Wg1 + l * 3 * DIMM;
            float texpr = own ? (x * Wg1_l[d] + res * Wg1_l[DIMM + d] + (x - res) * Wg1_l[2 * DIMM + d]) : 0.0f;
            float g1 = block_reduce_sum_8w(texpr, s_red);
            g1 = 1.0f / (1.0f + __expf(-g1));
            float n1 = x * g1 + res * (1.0f - g1);

            float m   = block_reduce_sum_8w(own ? n1 : 0.0f, s_red) * (1.0f / 128.0f);
            float df  = n1 - m;
            float var = block_reduce_sum_8w(own ? df * df : 0.0f, s_red) * (1.0f / 128.0f);
            float xnv = df * rsqrtf(var + 1e-5f) * ln2_g[l * DIMM + d] + ln2_b[l * DIMM + d];
            if (own) s_xn[d] = xnv;

            // FF1 fp16: 4 chunks x 32 rows, + exact gelu
            int c7 = t & 127, kg4 = t >> 7;
            const __half* W1L = hW1 + (size_t)l * DIMM * 4 * DIMM;
            stage32kB(W1L, buf0);
            {
                float4 ac1 = {0, 0, 0, 0};
                for (int cc = 0; cc < 4; cc++) {
                    __syncthreads();
                    if (cc < 3) stage32kB(W1L + (cc + 1) * 16384, (cc & 1) ? buf0 : buf1);
                    const float2* w2 = (const float2*)((cc & 1) ? buf1 : buf0);
#pragma unroll
                    for (int rr = 0; rr < 8; rr++) {
                        int row = kg4 * 8 + rr;
                        fma4h(ac1, s_xn[cc * 32 + row], w2[row * 128 + c7]);
                    }
                }
                ((float4*)(s_part + kg4 * 512))[c7] = ac1;
            }
            __syncthreads();
            {
                float a = b1[l * 4 * DIMM + t];
#pragma unroll
                for (int g = 0; g < 4; g++) a += s_part[g * 512 + t];
                a = 0.5f * a * (1.0f + erff(a * 0.70710678f));
                s_h[t] = a;
            }

            // FF2 fp16: 4 chunks x 128 rows
            const __half* W2L = hW2 + (size_t)l * 4 * DIMM * DIMM;
            stage32kB(W2L, buf0);
            {
                float4 ac2 = {0, 0, 0, 0};
                for (int cc = 0; cc < 4; cc++) {
                    __syncthreads();
                    if (cc < 3) stage32kB(W2L + (cc + 1) * 16384, (cc & 1) ? buf0 : buf1);
                    const float2* w2 = (const float2*)((cc & 1) ? buf1 : buf0);
#pragma unroll
                    for (int rr = 0; rr < 8; rr++) {
                        int row = kg16 * 8 + rr;
                        fma4h(ac2, s_h[cc * 128 + row], w2[row * 32 + c5]);
                    }
                }
                ((float4*)(s_part + kg16 * 128))[c5] = ac2;
            }
            __syncthreads();
            float y = 0.0f;
            if (own) {
                y = b2[l * DIMM + d];
#pragma unroll
                for (int g = 0; g < 16; g++) y += s_part[g * 128 + d];
            }

            const float* Wg2_l = Wg2 + l * 3 * DIMM;
            texpr = own ? (y * Wg2_l[d] + n1 * Wg2_l[DIMM + d] + (y - n1) * Wg2_l[2 * DIMM + d]) : 0.0f;
            float g2 = block_reduce_sum_8w(texpr, s_red);
            g2 = 1.0f / (1.0f + __expf(-g2));
            float n2 = y * g2 + n1 * (1.0f - g2);
            if (own) nodes[bn * DIMM + d] = n2;

            if (l < DEPTH - 1) {
                float m1   = block_reduce_sum_8w(own ? n2 : 0.0f, s_red) * (1.0f / 128.0f);
                float df1  = n2 - m1;
                float var1 = block_reduce_sum_8w(own ? df1 * df1 : 0.0f, s_red) * (1.0f / 128.0f);
                if (own) xn[bn * DIMM + d] = df1 * rsqrtf(var1 + 1e-5f) * ln1_g[(l + 1) * DIMM + d]
                                           + ln1_b[(l + 1) * DIMM + d];
            }
        }
        gridbar(bar, 2 + 2 * l);
    }

    // ================= Final: block 0 sums (nodes @ Wlin + blin) =================
    if (bx == 0) {
        if (t < 128) s_part[t] = Wlin[t];
        __syncthreads();
        float s = 0.0f;
        if (t < 256) {
            s = blin[0];
            const float4* nr = (const float4*)(nodes + t * DIMM);
#pragma unroll 8
            for (int q = 0; q < 32; q++) {
                float4 n = nr[q];
                s += n.x * s_part[4 * q] + n.y * s_part[4 * q + 1]
                   + n.z * s_part[4 * q + 2] + n.w * s_part[4 * q + 3];
            }
        }
#pragma unroll
        for (int off = 32; off > 0; off >>= 1) s += __shfl_xor(s, off, 64);
        int wave = t >> 6;
        if ((t & 63) == 0) s_red[wave] = s;
        __syncthreads();
        if (t == 0) out[0] = s_red[0] + s_red[1] + s_red[2] + s_red[3];
    }
}

extern "C" void kernel_launch(void* const* d_in, const int* in_sizes, int n_in,
                              void* d_out, int out_size, void* d_ws, size_t ws_size,
                              hipStream_t stream) {
    const int*   indices = (const int*)d_in[0];
    const float* coords  = (const float*)d_in[1];
    const int*   bonds   = (const int*)d_in[2];
    const float* noise   = (const float*)d_in[3];
    const float* atom_emb= (const float*)d_in[4];
    const float* ln1_g   = (const float*)d_in[5];
    const float* ln1_b   = (const float*)d_in[6];
    const float* Wq      = (const float*)d_in[7];
    const float* bq      = (const float*)d_in[8];
    const float* Wkv     = (const float*)d_in[9];
    const float* bkv     = (const float*)d_in[10];
    const float* We      = (const float*)d_in[11];
    const float* be      = (const float*)d_in[12];
    const float* Wo      = (const float*)d_in[13];
    const float* bo      = (const float*)d_in[14];
    const float* Wg1     = (const float*)d_in[15];
    const float* ln2_g   = (const float*)d_in[16];
    const float* ln2_b   = (const float*)d_in[17];
    const float* W1      = (const float*)d_in[18];
    const float* b1      = (const float*)d_in[19];
    const float* W2      = (const float*)d_in[20];
    const float* b2      = (const float*)d_in[21];
    const float* Wg2     = (const float*)d_in[22];
    const float* Wlin    = (const float*)d_in[23];
    const float* blin    = (const float*)d_in[24];

    char* base = (char*)d_ws;
    int*    bar   = (int*)base;
    float*  nodes = (float*)(base + 256);
    float*  xn    = nodes + NNODE * DIMM;
    float*  qb    = xn + NNODE * DIMM;
    __half* hk    = (__half*)(qb + NNODE * INNER);
    __half* hv    = hk + NNODE * INNER;
    __half* hWq   = hv + NNODE * INNER;
    __half* hWkv  = hWq + DEPTH * DIMM * INNER;
    __half* hWo   = hWkv + DEPTH * DIMM * 2 * INNER;
    __half* hW1   = hWo + DEPTH * INNER * DIMM;
    __half* hW2   = hW1 + DEPTH * DIMM * 4 * DIMM;

    k_init<<<1, 64, 0, stream>>>(bar);
    k_mega<<<GRID, 512, 0, stream>>>(indices, coords, bonds, noise, atom_emb,
                                     ln1_g, ln1_b, Wq, bq, Wkv, bkv, We, be,
                                     Wo, bo, Wg1, ln2_g, ln2_b, W1, b1, W2, b2,
                                     Wg2, Wlin, blin,
                                     bar, nodes, xn, qb, hk, hv,
                                     hWq, hWkv, hWo, hW1, hW2, (float*)d_out);
}

// Round 13
// 286.031 us; speedup vs baseline: 1.8162x; 1.8162x over previous
//
#include <hip/hip_runtime.h>
#include <hip/hip_fp16.h>
#include <math.h>

#define DEPTH 6
#define HEADS 8
#define BB    2
#define NN    128
#define EE    160
#define NF    127
#define DIMM  128
#define INNER 512
#define NNODE 256

__device__ __forceinline__ void gload16(const void* g, void* l) {
    __builtin_amdgcn_global_load_lds((const __attribute__((address_space(1))) void*)g,
                                     (__attribute__((address_space(3))) void*)l,
                                     16, 0, 0);
}

// wait this wave's outstanding vmem (vmcnt(0), lgkm/exp unconstrained)
__device__ __forceinline__ void wait_vm0() { __builtin_amdgcn_s_waitcnt(0x0f70); }

// Per-wave 16 KB contiguous stage: 16 x (1 KB gload16). ldsslice wave-uniform.
__device__ __forceinline__ void wstage16(const char* gslice, char* ldsslice, int ln) {
#pragma unroll
    for (int i = 0; i < 16; i++)
        gload16(gslice + i * 1024 + ln * 16, ldsslice + i * 1024);
}
// Strided variant: 16 rows of 1 KB, global row stride `rowstride` bytes.
__device__ __forceinline__ void wstage16s(const char* gslice, int rowstride,
                                          char* ldsslice, int ln) {
#pragma unroll
    for (int i = 0; i < 16; i++)
        gload16(gslice + (size_t)i * rowstride + ln * 16, ldsslice + i * 1024);
}

__device__ __forceinline__ void fma8h(float4& a0, float4& a1, float s, float4 raw) {
    const __half2* hp = (const __half2*)&raw;
    float2 p0 = __half22float2(hp[0]), p1 = __half22float2(hp[1]);
    float2 p2 = __half22float2(hp[2]), p3 = __half22float2(hp[3]);
    a0.x += s * p0.x; a0.y += s * p0.y; a0.z += s * p1.x; a0.w += s * p1.y;
    a1.x += s * p2.x; a1.y += s * p2.y; a1.z += s * p3.x; a1.w += s * p3.y;
}

// GEMV unit, C=512 K=128, wave w owns rows [w*16, w*16+16). wbuf = 16 rows x 1KB.
__device__ __forceinline__ void gemv512(const float* act, const float* wbuf,
                                        float* s_part, int w, int ln) {
    float4 a0 = {0,0,0,0}, a1 = {0,0,0,0};
    const float4* w4 = (const float4*)wbuf;
#pragma unroll
    for (int r = 0; r < 16; r++)
        fma8h(a0, a1, act[w * 16 + r], w4[r * 64 + ln]);
    ((float4*)(s_part + w * 512))[ln * 2]     = a0;
    ((float4*)(s_part + w * 512))[ln * 2 + 1] = a1;
}

// GEMV unit, C=128 K=512, wave w owns rows [w*64, w*64+64). wbuf = 64 rows x 256B.
__device__ __forceinline__ void gemv128(const float* act, const float* wbuf,
                                        float* s_part, int w, int ln) {
    float2 acc = {0, 0};
#pragma unroll 8
    for (int r = 0; r < 64; r++) {
        float raw = wbuf[r * 64 + ln];
        __half2 h = *(__half2*)&raw;
        float2 p = __half22float2(h);
        float a = act[w * 64 + r];
        acc.x += a * p.x; acc.y += a * p.y;
    }
    s_part[w * 128 + ln * 2]     = acc.x;
    s_part[w * 128 + ln * 2 + 1] = acc.y;
}

__device__ __forceinline__ float block_reduce_sum_8w(float val, float* sbuf) {
#pragma unroll
    for (int off = 32; off > 0; off >>= 1) val += __shfl_xor(val, off, 64);
    int wave = threadIdx.x >> 6;
    if ((threadIdx.x & 63) == 0) sbuf[wave] = val;
    __syncthreads();
    float r = sbuf[0] + sbuf[1] + sbuf[2] + sbuf[3] + sbuf[4] + sbuf[5] + sbuf[6] + sbuf[7];
    __syncthreads();
    return r;
}

// QKV for node bn from s_xn (LN1 output). 3 per-wave-streamed units.
__device__ void qkv_wave(int t, int bn, int layer,
                         const __half* hWq, const float* bq,
                         const __half* hWkv, const float* bkv,
                         float* qb, __half* hk, __half* hv,
                         const float* s_xn, float* s_part, float* arena) {
    int w = t >> 6, ln = t & 63;
    char*  lslice = (char*)arena + w * 16384;
    float* wbuf   = arena + w * 4096;

    // Wq [128 x 512]
    const char* WqL = (const char*)(hWq + (size_t)layer * DIMM * INNER);
    wstage16(WqL + w * 16384, lslice, ln);
    wait_vm0();
    gemv512(s_xn, wbuf, s_part, w, ln);
    __syncthreads();
    {
        float q = bq[layer * INNER + t];
#pragma unroll
        for (int g = 0; g < 8; g++) q += s_part[g * 512 + t];
        qb[(size_t)bn * INNER + t] = q;
    }
    __syncthreads();

    // Wk: cols [0,512) of Wkv [128 x 1024]
    const char* WkvL = (const char*)(hWkv + (size_t)layer * DIMM * 2 * INNER);
    wstage16s(WkvL + (size_t)(w * 16) * 2048, 2048, lslice, ln);
    wait_vm0();
    gemv512(s_xn, wbuf, s_part, w, ln);
    __syncthreads();
    {
        float k = bkv[layer * 2 * INNER + t];
#pragma unroll
        for (int g = 0; g < 8; g++) k += s_part[g * 512 + t];
        hk[(size_t)bn * INNER + t] = __float2half(k);
    }
    __syncthreads();

    // Wv: cols [512,1024)
    wstage16s(WkvL + (size_t)(w * 16) * 2048 + 1024, 2048, lslice, ln);
    wait_vm0();
    gemv512(s_xn, wbuf, s_part, w, ln);
    __syncthreads();
    {
        float v = bkv[layer * 2 * INNER + INNER + t];
#pragma unroll
        for (int g = 0; g < 8; g++) v += s_part[g * 512 + t];
        hv[(size_t)bn * INNER + t] = __float2half(v);
    }
    __syncthreads();
}

// ---------- kernels ----------

// fp32 -> fp16 weight convert (separate kernel: dispatch-end flush leaves
// clean lines -> later cross-XCD reads are L3 hits, not dirty-flush traffic).
__global__ __launch_bounds__(512) void k_cvt(const float* Wq, const float* Wkv,
                                             const float* Wo, const float* W1,
                                             const float* W2,
                                             __half* hWq, __half* hWkv, __half* hWo,
                                             __half* hW1, __half* hW2) {
    int g = blockIdx.x * 512 + threadIdx.x;
    const float4* src; __half* dst; int off;
    if (g < 98304)       { src = (const float4*)Wq;  dst = hWq;  off = g; }
    else if (g < 294912) { src = (const float4*)Wkv; dst = hWkv; off = g - 98304; }
    else if (g < 393216) { src = (const float4*)Wo;  dst = hWo;  off = g - 294912; }
    else if (g < 491520) { src = (const float4*)W1;  dst = hW1;  off = g - 393216; }
    else                 { src = (const float4*)W2;  dst = hW2;  off = g - 491520; }
    float4 v = src[off];
    __half2* d2 = (__half2*)(dst + (size_t)off * 4);
    d2[0] = __floats2half2_rn(v.x, v.y);
    d2[1] = __floats2half2_rn(v.z, v.w);
}

__global__ __launch_bounds__(512, 1) void k_pre(const int* indices, const float* noise,
                                                const float* atom_emb,
                                                const float* ln1_g, const float* ln1_b,
                                                const __half* hWq, const float* bq,
                                                const __half* hWkv, const float* bkv,
                                                float* nodes, float* qb,
                                                __half* hk, __half* hv) {
    int bn = blockIdx.x;
    int t  = threadIdx.x;
    int d  = t & 127;
    bool own = (t < 128);
    __shared__ float arena[32768];
    __shared__ float s_xn[128];
    __shared__ float s_red[8];
    __shared__ float s_part[4096];

    float nd = 0.0f;
    if (own) {
        int idx = indices[bn];
        nd = (d < NF) ? atom_emb[idx * NF + d] : noise[0];
        nodes[bn * DIMM + d] = nd;
    }
    float m   = block_reduce_sum_8w(own ? nd : 0.0f, s_red) * (1.0f / 128.0f);
    float df  = nd - m;
    float var = block_reduce_sum_8w(own ? df * df : 0.0f, s_red) * (1.0f / 128.0f);
    if (own) s_xn[d] = df * rsqrtf(var + 1e-5f) * ln1_g[d] + ln1_b[d];
    __syncthreads();

    qkv_wave(t, bn, 0, hWq, bq, hWkv, bkv, qb, hk, hv, s_xn, s_part, arena);
}

__global__ __launch_bounds__(512, 1) void k_layer(int l,
        const float* coords, const int* bonds,
        const float* We, const float* be,
        float* qb, const __half* hkin, const __half* hvin,
        __half* hkout, __half* hvout,
        const __half* hWo, const float* bo, const float* Wg1,
        const float* ln2_g, const float* ln2_b,
        const __half* hW1, const float* b1,
        const __half* hW2, const float* b2,
        const float* Wg2,
        const float* ln1_g, const float* ln1_b,
        const __half* hWq, const float* bq,
        const __half* hWkv, const float* bkv,
        float* nodes) {
    int bn = blockIdx.x;
    int b = bn >> 7, i = bn & 127;
    int t = threadIdx.x;
    int d = t & 127;
    bool own = (t < 128);
    int w = t >> 6, ln = t & 63;

    __shared__ float arena[32768];     // attention: s_o alias; GEMV: wave slices
    __shared__ float scoord[384];
    __shared__ float sedge[384];
    __shared__ int   sadj[128];
    __shared__ float s_l[32];
    __shared__ float s_ao[512];
    __shared__ float s_h[512];
    __shared__ float s_xn[128];
    __shared__ float s_red[8];
    __shared__ float s_part[4096];
    float* s_o = arena;
    char*  lslice = (char*)arena + w * 16384;
    float* wbuf   = arena + w * 4096;

    // ---------- attention ----------
    int jg = t >> 7, c = t & 127, h = c >> 4;
    const float4* qR  = (const float4*)(qb + (size_t)bn * INNER);
    const float4* WeR = (const float4*)(We + (size_t)l * 3 * INNER);
    float4 qv  = qR[c];
    float4 we0 = WeR[c], we1 = WeR[128 + c], we2 = WeR[256 + c];
    float4 bev = ((const float4*)(be + (size_t)l * INNER))[c];
    float res = own ? nodes[bn * DIMM + d] : 0.0f;

    if (t < 3 * NN) scoord[t] = coords[b * 3 * NN + t];
    if (t < NN) sadj[t] = 0;
    __syncthreads();
    if (t < EE) {
        int e0 = bonds[2 * t], e1 = bonds[2 * t + 1];
        if (e0 == i) sadj[e1] = 1;
        if (e1 == i) sadj[e0] = 1;
    }
    __syncthreads();
    if (t < NN) {
        int j = t;
        float msk = sadj[j] ? 1.0f : 0.0f;
        sedge[3 * j + 0] = msk * (scoord[3 * i + 0] - scoord[3 * j + 0]);
        sedge[3 * j + 1] = msk * (scoord[3 * i + 1] - scoord[3 * j + 1]);
        sedge[3 * j + 2] = msk * (scoord[3 * i + 2] - scoord[3 * j + 2]);
    }
    __syncthreads();

    const float2* kR2 = (const float2*)(hkin + (size_t)b * NN * INNER);
    const float2* vR2 = (const float2*)(hvin + (size_t)b * NN * INNER);
    float l_run = 0.0f;
    float4 o_run = {0, 0, 0, 0};
    int j0 = jg * 32;
#pragma unroll
    for (int base = 0; base < 32; base += 8) {
        float2 kraw[8], vraw[8];
#pragma unroll
        for (int p = 0; p < 8; p++) {
            int j = j0 + base + p;
            kraw[p] = kR2[j * 128 + c];
            vraw[p] = vR2[j * 128 + c];
        }
#pragma unroll
        for (int p = 0; p < 8; p++) {
            int j = j0 + base + p;
            float ex = sedge[3 * j], ey = sedge[3 * j + 1], ez = sedge[3 * j + 2];
            float4 e;
            e.x = bev.x + ex * we0.x + ey * we1.x + ez * we2.x;
            e.y = bev.y + ex * we0.y + ey * we1.y + ez * we2.y;
            e.z = bev.z + ex * we0.z + ey * we1.z + ez * we2.z;
            e.w = bev.w + ex * we0.w + ey * we1.w + ez * we2.w;
            const __half2* kh = (const __half2*)&kraw[p];
            float2 k01 = __half22float2(kh[0]), k23 = __half22float2(kh[1]);
            float s = (qv.x * (k01.x + e.x) + qv.y * (k01.y + e.y))
                    + (qv.z * (k23.x + e.z) + qv.w * (k23.y + e.w));
            s += __shfl_xor(s, 1, 64);
            s += __shfl_xor(s, 2, 64);
            s += __shfl_xor(s, 4, 64);
            s += __shfl_xor(s, 8, 64);
            float pp = __expf(s * 0.125f);
            const __half2* vh = (const __half2*)&vraw[p];
            float2 v01 = __half22float2(vh[0]), v23 = __half22float2(vh[1]);
            l_run += pp;
            o_run.x += pp * (v01.x + e.x);
            o_run.y += pp * (v01.y + e.y);
            o_run.z += pp * (v23.x + e.z);
            o_run.w += pp * (v23.y + e.w);
        }
    }
    ((float4*)(s_o + jg * INNER))[c] = o_run;
    if ((c & 15) == 0) s_l[jg * HEADS + h] = l_run;
    __syncthreads();
    if (jg == 0) {
        float4 o = o_run;
        float lsum = l_run;
#pragma unroll
        for (int g = 1; g < 4; g++) {
            float4 og = ((float4*)(s_o + g * INNER))[c];
            o.x += og.x; o.y += og.y; o.z += og.z; o.w += og.w;
            lsum += s_l[g * HEADS + h];
        }
        float inv = 1.0f / lsum;
        float4 rr; rr.x = o.x * inv; rr.y = o.y * inv; rr.z = o.z * inv; rr.w = o.w * inv;
        ((float4*)s_ao)[c] = rr;
    }
    __syncthreads();   // s_o (arena) free after this

    // ---------- Wo [512 x 128] ----------
    const char* WoL = (const char*)(hWo + (size_t)l * INNER * DIMM);
    wstage16(WoL + w * 16384, lslice, ln);
    wait_vm0();
    gemv128(s_ao, wbuf, s_part, w, ln);
    __syncthreads();
    float x = 0.0f;
    if (own) {
        x = bo[l * DIMM + d];
#pragma unroll
        for (int g = 0; g < 8; g++) x += s_part[g * 128 + d];
    }
    __syncthreads();

    // gate1
    const float* Wg1_l = Wg1 + l * 3 * DIMM;
    float texpr = own ? (x * Wg1_l[d] + res * Wg1_l[DIMM + d] + (x - res) * Wg1_l[2 * DIMM + d]) : 0.0f;
    float g1 = block_reduce_sum_8w(texpr, s_red);
    g1 = 1.0f / (1.0f + __expf(-g1));
    float n1 = x * g1 + res * (1.0f - g1);

    // LN2
    float m   = block_reduce_sum_8w(own ? n1 : 0.0f, s_red) * (1.0f / 128.0f);
    float df  = n1 - m;
    float var = block_reduce_sum_8w(own ? df * df : 0.0f, s_red) * (1.0f / 128.0f);
    if (own) s_xn[d] = df * rsqrtf(var + 1e-5f) * ln2_g[l * DIMM + d] + ln2_b[l * DIMM + d];
    __syncthreads();

    // ---------- W1 [128 x 512] + gelu ----------
    const char* W1L = (const char*)(hW1 + (size_t)l * DIMM * 4 * DIMM);
    wstage16(W1L + w * 16384, lslice, ln);
    wait_vm0();
    gemv512(s_xn, wbuf, s_part, w, ln);
    __syncthreads();
    {
        float a = b1[l * 4 * DIMM + t];
#pragma unroll
        for (int g = 0; g < 8; g++) a += s_part[g * 512 + t];
        a = 0.5f * a * (1.0f + erff(a * 0.70710678f));
        s_h[t] = a;
    }
    __syncthreads();

    // ---------- W2 [512 x 128] ----------
    const char* W2L = (const char*)(hW2 + (size_t)l * 4 * DIMM * DIMM);
    wstage16(W2L + w * 16384, lslice, ln);
    wait_vm0();
    gemv128(s_h, wbuf, s_part, w, ln);
    __syncthreads();
    float y = 0.0f;
    if (own) {
        y = b2[l * DIMM + d];
#pragma unroll
        for (int g = 0; g < 8; g++) y += s_part[g * 128 + d];
    }
    __syncthreads();

    // gate2
    const float* Wg2_l = Wg2 + l * 3 * DIMM;
    texpr = own ? (y * Wg2_l[d] + n1 * Wg2_l[DIMM + d] + (y - n1) * Wg2_l[2 * DIMM + d]) : 0.0f;
    float g2 = block_reduce_sum_8w(texpr, s_red);
    g2 = 1.0f / (1.0f + __expf(-g2));
    float n2 = y * g2 + n1 * (1.0f - g2);
    if (own) nodes[bn * DIMM + d] = n2;

    if (l < DEPTH - 1) {
        float m1   = block_reduce_sum_8w(own ? n2 : 0.0f, s_red) * (1.0f / 128.0f);
        float df1  = n2 - m1;
        float var1 = block_reduce_sum_8w(own ? df1 * df1 : 0.0f, s_red) * (1.0f / 128.0f);
        if (own) s_xn[d] = df1 * rsqrtf(var1 + 1e-5f) * ln1_g[(l + 1) * DIMM + d]
                         + ln1_b[(l + 1) * DIMM + d];
        __syncthreads();
        qkv_wave(t, bn, l + 1, hWq, bq, hWkv, bkv, qb, hkout, hvout,
                 s_xn, s_part, arena);
    }
}

__global__ __launch_bounds__(256) void k_final(const float* nodes, const float* Wlin,
                                               const float* blin, float* out) {
    int t = threadIdx.x;
    __shared__ float s_w[DIMM];
    if (t < DIMM) s_w[t] = Wlin[t];
    __syncthreads();
    float s = blin[0];
    const float4* nr = (const float4*)(nodes + t * DIMM);
#pragma unroll 8
    for (int q = 0; q < 32; q++) {
        float4 n = nr[q];
        s += n.x * s_w[4 * q] + n.y * s_w[4 * q + 1] + n.z * s_w[4 * q + 2] + n.w * s_w[4 * q + 3];
    }
#pragma unroll
    for (int off = 32; off > 0; off >>= 1) s += __shfl_xor(s, off, 64);
    __shared__ float sb[4];
    int wave = t >> 6, lane = t & 63;
    if (lane == 0) sb[wave] = s;
    __syncthreads();
    if (t == 0) out[0] = sb[0] + sb[1] + sb[2] + sb[3];
}

extern "C" void kernel_launch(void* const* d_in, const int* in_sizes, int n_in,
                              void* d_out, int out_size, void* d_ws, size_t ws_size,
                              hipStream_t stream) {
    const int*   indices = (const int*)d_in[0];
    const float* coords  = (const float*)d_in[1];
    const int*   bonds   = (const int*)d_in[2];
    const float* noise   = (const float*)d_in[3];
    const float* atom_emb= (const float*)d_in[4];
    const float* ln1_g   = (const float*)d_in[5];
    const float* ln1_b   = (const float*)d_in[6];
    const float* Wq      = (const float*)d_in[7];
    const float* bq      = (const float*)d_in[8];
    const float* Wkv     = (const float*)d_in[9];
    const float* bkv     = (const float*)d_in[10];
    const float* We      = (const float*)d_in[11];
    const float* be      = (const float*)d_in[12];
    const float* Wo      = (const float*)d_in[13];
    const float* bo      = (const float*)d_in[14];
    const float* Wg1     = (const float*)d_in[15];
    const float* ln2_g   = (const float*)d_in[16];
    const float* ln2_b   = (const float*)d_in[17];
    const float* W1      = (const float*)d_in[18];
    const float* b1      = (const float*)d_in[19];
    const float* W2      = (const float*)d_in[20];
    const float* b2      = (const float*)d_in[21];
    const float* Wg2     = (const float*)d_in[22];
    const float* Wlin    = (const float*)d_in[23];
    const float* blin    = (const float*)d_in[24];

    float*  ws    = (float*)d_ws;
    float*  nodes = ws;                         // 32768 f
    float*  qb    = nodes + NNODE * DIMM;       // 131072 f
    __half* hkb   = (__half*)(qb + NNODE * INNER);  // 2 slabs x 131072 halves
    __half* hvb   = hkb + 2 * NNODE * INNER;
    __half* hWq   = hvb + 2 * NNODE * INNER;
    __half* hWkv  = hWq + DEPTH * DIMM * INNER;
    __half* hWo   = hWkv + DEPTH * DIMM * 2 * INNER;
    __half* hW1   = hWo + DEPTH * INNER * DIMM;
    __half* hW2   = hW1 + DEPTH * DIMM * 4 * DIMM;

    k_cvt<<<1152, 512, 0, stream>>>(Wq, Wkv, Wo, W1, W2, hWq, hWkv, hWo, hW1, hW2);
    k_pre<<<NNODE, 512, 0, stream>>>(indices, noise, atom_emb, ln1_g, ln1_b,
                                     hWq, bq, hWkv, bkv, nodes, qb, hkb, hvb);
    for (int l = 0; l < DEPTH; l++) {
        const __half* hkin = hkb + (size_t)(l & 1) * NNODE * INNER;
        const __half* hvin = hvb + (size_t)(l & 1) * NNODE * INNER;
        __half* hkout = hkb + (size_t)((l + 1) & 1) * NNODE * INNER;
        __half* hvout = hvb + (size_t)((l + 1) & 1) * NNODE * INNER;
        k_layer<<<NNODE, 512, 0, stream>>>(l, coords, bonds, We, be,
                                           qb, hkin, hvin, hkout, hvout,
                                           hWo, bo, Wg1, ln2_g, ln2_b, hW1, b1, hW2, b2,
                                           Wg2, ln1_g, ln1_b, hWq, bq, hWkv, bkv, nodes);
    }
    k_final<<<1, 256, 0, stream>>>(nodes, Wlin, blin, (float*)d_out);
}

// Round 14
// 281.862 us; speedup vs baseline: 1.8430x; 1.0148x over previous
//
#include <hip/hip_runtime.h>
#include <hip/hip_fp16.h>
#include <math.h>

#define DEPTH 6
#define HEADS 8
#define BB    2
#define NN    128
#define EE    160
#define NF    127
#define DIMM  128
#define INNER 512
#define NNODE 256

__device__ __forceinline__ void gload16(const void* g, void* l) {
    __builtin_amdgcn_global_load_lds((const __attribute__((address_space(1))) void*)g,
                                     (__attribute__((address_space(3))) void*)l,
                                     16, 0, 0);
}

// wait this wave's outstanding vmem (vmcnt(0); lgkm/exp unconstrained)
__device__ __forceinline__ void wait_vm0() { __builtin_amdgcn_s_waitcnt(0x0f70); }
// drain this wave's LDS ops (lgkmcnt(0); vm/exp unconstrained) before slice overwrite
__device__ __forceinline__ void wait_lgkm0() { __builtin_amdgcn_s_waitcnt(0xC07F); }

// Per-wave 16 KB contiguous stage: 16 x (1 KB gload16). ldsslice wave-uniform.
__device__ __forceinline__ void wstage16(const char* gslice, char* ldsslice, int ln) {
#pragma unroll
    for (int i = 0; i < 16; i++)
        gload16(gslice + i * 1024 + ln * 16, ldsslice + i * 1024);
}
// Strided variant: 16 rows of 1 KB, global row stride `rowstride` bytes.
__device__ __forceinline__ void wstage16s(const char* gslice, int rowstride,
                                          char* ldsslice, int ln) {
#pragma unroll
    for (int i = 0; i < 16; i++)
        gload16(gslice + (size_t)i * rowstride + ln * 16, ldsslice + i * 1024);
}

__device__ __forceinline__ void fma8h(float4& a0, float4& a1, float s, float4 raw) {
    const __half2* hp = (const __half2*)&raw;
    float2 p0 = __half22float2(hp[0]), p1 = __half22float2(hp[1]);
    float2 p2 = __half22float2(hp[2]), p3 = __half22float2(hp[3]);
    a0.x += s * p0.x; a0.y += s * p0.y; a0.z += s * p1.x; a0.w += s * p1.y;
    a1.x += s * p2.x; a1.y += s * p2.y; a1.z += s * p3.x; a1.w += s * p3.y;
}

// GEMV unit, C=512 K=128, wave w owns rows [w*16, w*16+16). wbuf = 16 rows x 1KB.
__device__ __forceinline__ void gemv512(const float* act, const float* wbuf,
                                        float* s_part, int w, int ln) {
    float4 a0 = {0,0,0,0}, a1 = {0,0,0,0};
    const float4* w4 = (const float4*)wbuf;
#pragma unroll
    for (int r = 0; r < 16; r++)
        fma8h(a0, a1, act[w * 16 + r], w4[r * 64 + ln]);
    ((float4*)(s_part + w * 512))[ln * 2]     = a0;
    ((float4*)(s_part + w * 512))[ln * 2 + 1] = a1;
}

// GEMV unit, C=128 K=512, wave w owns rows [w*64, w*64+64). wbuf = 64 rows x 256B.
__device__ __forceinline__ void gemv128(const float* act, const float* wbuf,
                                        float* s_part, int w, int ln) {
    float2 acc = {0, 0};
#pragma unroll 8
    for (int r = 0; r < 64; r++) {
        float raw = wbuf[r * 64 + ln];
        __half2 h = *(__half2*)&raw;
        float2 p = __half22float2(h);
        float a = act[w * 64 + r];
        acc.x += a * p.x; acc.y += a * p.y;
    }
    s_part[w * 128 + ln * 2]     = acc.x;
    s_part[w * 128 + ln * 2 + 1] = acc.y;
}

__device__ __forceinline__ float block_reduce_sum_8w(float val, float* sbuf) {
#pragma unroll
    for (int off = 32; off > 0; off >>= 1) val += __shfl_xor(val, off, 64);
    int wave = threadIdx.x >> 6;
    if ((threadIdx.x & 63) == 0) sbuf[wave] = val;
    __syncthreads();
    float r = sbuf[0] + sbuf[1] + sbuf[2] + sbuf[3] + sbuf[4] + sbuf[5] + sbuf[6] + sbuf[7];
    __syncthreads();
    return r;
}

// ---------- kernels ----------

__global__ __launch_bounds__(512) void k_cvt(const float* Wq, const float* Wkv,
                                             const float* Wo, const float* W1,
                                             const float* W2,
                                             __half* hWq, __half* hWkv, __half* hWo,
                                             __half* hW1, __half* hW2) {
    int g = blockIdx.x * 512 + threadIdx.x;
    const float4* src; __half* dst; int off;
    if (g < 98304)       { src = (const float4*)Wq;  dst = hWq;  off = g; }
    else if (g < 294912) { src = (const float4*)Wkv; dst = hWkv; off = g - 98304; }
    else if (g < 393216) { src = (const float4*)Wo;  dst = hWo;  off = g - 294912; }
    else if (g < 491520) { src = (const float4*)W1;  dst = hW1;  off = g - 393216; }
    else                 { src = (const float4*)W2;  dst = hW2;  off = g - 491520; }
    float4 v = src[off];
    __half2* d2 = (__half2*)(dst + (size_t)off * 4);
    d2[0] = __floats2half2_rn(v.x, v.y);
    d2[1] = __floats2half2_rn(v.z, v.w);
}

__global__ __launch_bounds__(512, 1) void k_pre(const int* indices, const float* noise,
                                                const float* atom_emb,
                                                const float* ln1_g, const float* ln1_b,
                                                const __half* hWq, const float* bq,
                                                const __half* hWkv, const float* bkv,
                                                float* nodes, float* qb,
                                                __half* hk, __half* hv) {
    int bn = blockIdx.x;
    int t  = threadIdx.x;
    int d  = t & 127;
    bool own = (t < 128);
    int w = t >> 6, ln = t & 63;
    __shared__ float arena[32768];
    __shared__ float s_xn[128];
    __shared__ float s_red[8];
    __shared__ float s_part[4096];
    char*  lslice = (char*)arena + w * 16384;
    float* wbuf   = arena + w * 4096;

    // stage Wq immediately; DMA overlaps gather + LN
    const char* WqL  = (const char*)(hWq + 0);
    const char* WkvL = (const char*)(hWkv + 0);
    wstage16(WqL + w * 16384, lslice, ln);

    float nd = 0.0f;
    if (own) {
        int idx = indices[bn];
        nd = (d < NF) ? atom_emb[idx * NF + d] : noise[0];
        nodes[bn * DIMM + d] = nd;
    }
    float m   = block_reduce_sum_8w(own ? nd : 0.0f, s_red) * (1.0f / 128.0f);
    float df  = nd - m;
    float var = block_reduce_sum_8w(own ? df * df : 0.0f, s_red) * (1.0f / 128.0f);
    if (own) s_xn[d] = df * rsqrtf(var + 1e-5f) * ln1_g[d] + ln1_b[d];
    __syncthreads();

    // Wq
    wait_vm0();
    gemv512(s_xn, wbuf, s_part, w, ln);
    wait_lgkm0();
    wstage16s(WkvL + (size_t)(w * 16) * 2048, 2048, lslice, ln);   // Wk
    __syncthreads();
    {
        float q = bq[t];
#pragma unroll
        for (int g = 0; g < 8; g++) q += s_part[g * 512 + t];
        qb[(size_t)bn * INNER + t] = q;
    }
    __syncthreads();

    // Wk
    wait_vm0();
    gemv512(s_xn, wbuf, s_part, w, ln);
    wait_lgkm0();
    wstage16s(WkvL + (size_t)(w * 16) * 2048 + 1024, 2048, lslice, ln);   // Wv
    __syncthreads();
    {
        float k = bkv[t];
#pragma unroll
        for (int g = 0; g < 8; g++) k += s_part[g * 512 + t];
        hk[(size_t)bn * INNER + t] = __float2half(k);
    }
    __syncthreads();

    // Wv
    wait_vm0();
    gemv512(s_xn, wbuf, s_part, w, ln);
    __syncthreads();
    {
        float v = bkv[INNER + t];
#pragma unroll
        for (int g = 0; g < 8; g++) v += s_part[g * 512 + t];
        hv[(size_t)bn * INNER + t] = __float2half(v);
    }
}

__global__ __launch_bounds__(512, 1) void k_layer(int l,
        const float* coords, const int* bonds,
        const float* We, const float* be,
        float* qb, const __half* hkin, const __half* hvin,
        __half* hkout, __half* hvout,
        const __half* hWo, const float* bo, const float* Wg1,
        const float* ln2_g, const float* ln2_b,
        const __half* hW1, const float* b1,
        const __half* hW2, const float* b2,
        const float* Wg2,
        const float* ln1_g, const float* ln1_b,
        const __half* hWq, const float* bq,
        const __half* hWkv, const float* bkv,
        float* nodes) {
    int bn = blockIdx.x;
    int b = bn >> 7, i = bn & 127;
    int t = threadIdx.x;
    int d = t & 127;
    bool own = (t < 128);
    int w = t >> 6, ln = t & 63;

    __shared__ float arena[32768];     // per-wave weight slices (16 KB each)
    __shared__ float scoord[384];
    __shared__ float sedge[384];
    __shared__ int   sadj[128];
    __shared__ float s_l[32];
    __shared__ float s_ao[512];
    __shared__ float s_h[512];
    __shared__ float s_xn[128];
    __shared__ float s_red[8];
    __shared__ float s_part[4096];     // also aliased as s_o during attention
    float* s_o = s_part;
    char*  lslice = (char*)arena + w * 16384;
    float* wbuf   = arena + w * 4096;

    const char* WoL  = (const char*)(hWo + (size_t)l * INNER * DIMM);
    const char* W1L  = (const char*)(hW1 + (size_t)l * DIMM * 4 * DIMM);
    const char* W2L  = (const char*)(hW2 + (size_t)l * 4 * DIMM * DIMM);
    const char* WqL  = (const char*)(hWq + (size_t)(l + 1) * DIMM * INNER);
    const char* WkvL = (const char*)(hWkv + (size_t)(l + 1) * DIMM * 2 * INNER);

    // stage Wo immediately; DMA overlaps the whole attention phase
    wstage16(WoL + w * 16384, lslice, ln);

    // ---------- attention ----------
    int jg = t >> 7, c = t & 127, h = c >> 4;
    const float4* qR  = (const float4*)(qb + (size_t)bn * INNER);
    const float4* WeR = (const float4*)(We + (size_t)l * 3 * INNER);
    float4 qv  = qR[c];
    float4 we0 = WeR[c], we1 = WeR[128 + c], we2 = WeR[256 + c];
    float4 bev = ((const float4*)(be + (size_t)l * INNER))[c];
    float res = own ? nodes[bn * DIMM + d] : 0.0f;

    if (t < 3 * NN) scoord[t] = coords[b * 3 * NN + t];
    if (t < NN) sadj[t] = 0;
    __syncthreads();
    if (t < EE) {
        int e0 = bonds[2 * t], e1 = bonds[2 * t + 1];
        if (e0 == i) sadj[e1] = 1;
        if (e1 == i) sadj[e0] = 1;
    }
    __syncthreads();
    if (t < NN) {
        int j = t;
        float msk = sadj[j] ? 1.0f : 0.0f;
        sedge[3 * j + 0] = msk * (scoord[3 * i + 0] - scoord[3 * j + 0]);
        sedge[3 * j + 1] = msk * (scoord[3 * i + 1] - scoord[3 * j + 1]);
        sedge[3 * j + 2] = msk * (scoord[3 * i + 2] - scoord[3 * j + 2]);
    }
    __syncthreads();

    const float2* kR2 = (const float2*)(hkin + (size_t)b * NN * INNER);
    const float2* vR2 = (const float2*)(hvin + (size_t)b * NN * INNER);
    float l_run = 0.0f;
    float4 o_run = {0, 0, 0, 0};
    int j0 = jg * 32;
#pragma unroll
    for (int base = 0; base < 32; base += 8) {
        float2 kraw[8], vraw[8];
#pragma unroll
        for (int p = 0; p < 8; p++) {
            int j = j0 + base + p;
            kraw[p] = kR2[j * 128 + c];
            vraw[p] = vR2[j * 128 + c];
        }
#pragma unroll
        for (int p = 0; p < 8; p++) {
            int j = j0 + base + p;
            float ex = sedge[3 * j], ey = sedge[3 * j + 1], ez = sedge[3 * j + 2];
            float4 e;
            e.x = bev.x + ex * we0.x + ey * we1.x + ez * we2.x;
            e.y = bev.y + ex * we0.y + ey * we1.y + ez * we2.y;
            e.z = bev.z + ex * we0.z + ey * we1.z + ez * we2.z;
            e.w = bev.w + ex * we0.w + ey * we1.w + ez * we2.w;
            const __half2* kh = (const __half2*)&kraw[p];
            float2 k01 = __half22float2(kh[0]), k23 = __half22float2(kh[1]);
            float s = (qv.x * (k01.x + e.x) + qv.y * (k01.y + e.y))
                    + (qv.z * (k23.x + e.z) + qv.w * (k23.y + e.w));
            s += __shfl_xor(s, 1, 64);
            s += __shfl_xor(s, 2, 64);
            s += __shfl_xor(s, 4, 64);
            s += __shfl_xor(s, 8, 64);
            float pp = __expf(s * 0.125f);
            const __half2* vh = (const __half2*)&vraw[p];
            float2 v01 = __half22float2(vh[0]), v23 = __half22float2(vh[1]);
            l_run += pp;
            o_run.x += pp * (v01.x + e.x);
            o_run.y += pp * (v01.y + e.y);
            o_run.z += pp * (v23.x + e.z);
            o_run.w += pp * (v23.y + e.w);
        }
    }
    ((float4*)(s_o + jg * INNER))[c] = o_run;
    if ((c & 15) == 0) s_l[jg * HEADS + h] = l_run;
    __syncthreads();
    if (jg == 0) {
        float4 o = o_run;
        float lsum = l_run;
#pragma unroll
        for (int g = 1; g < 4; g++) {
            float4 og = ((float4*)(s_o + g * INNER))[c];
            o.x += og.x; o.y += og.y; o.z += og.z; o.w += og.w;
            lsum += s_l[g * HEADS + h];
        }
        float inv = 1.0f / lsum;
        float4 rr; rr.x = o.x * inv; rr.y = o.y * inv; rr.z = o.z * inv; rr.w = o.w * inv;
        ((float4*)s_ao)[c] = rr;
    }
    __syncthreads();

    // ---------- Wo [512 x 128] ----------
    wait_vm0();
    gemv128(s_ao, wbuf, s_part, w, ln);
    wait_lgkm0();
    wstage16(W1L + w * 16384, lslice, ln);   // issue W1 DMA; flies during gate1/LN2
    __syncthreads();
    float x = 0.0f;
    if (own) {
        x = bo[l * DIMM + d];
#pragma unroll
        for (int g = 0; g < 8; g++) x += s_part[g * 128 + d];
    }
    __syncthreads();

    // gate1
    const float* Wg1_l = Wg1 + l * 3 * DIMM;
    float texpr = own ? (x * Wg1_l[d] + res * Wg1_l[DIMM + d] + (x - res) * Wg1_l[2 * DIMM + d]) : 0.0f;
    float g1 = block_reduce_sum_8w(texpr, s_red);
    g1 = 1.0f / (1.0f + __expf(-g1));
    float n1 = x * g1 + res * (1.0f - g1);

    // LN2
    float m   = block_reduce_sum_8w(own ? n1 : 0.0f, s_red) * (1.0f / 128.0f);
    float df  = n1 - m;
    float var = block_reduce_sum_8w(own ? df * df : 0.0f, s_red) * (1.0f / 128.0f);
    if (own) s_xn[d] = df * rsqrtf(var + 1e-5f) * ln2_g[l * DIMM + d] + ln2_b[l * DIMM + d];
    __syncthreads();

    // ---------- W1 [128 x 512] + gelu ----------
    wait_vm0();
    gemv512(s_xn, wbuf, s_part, w, ln);
    wait_lgkm0();
    wstage16(W2L + w * 16384, lslice, ln);   // issue W2 DMA; flies during gelu combine
    __syncthreads();
    {
        float a = b1[l * 4 * DIMM + t];
#pragma unroll
        for (int g = 0; g < 8; g++) a += s_part[g * 512 + t];
        a = 0.5f * a * (1.0f + erff(a * 0.70710678f));
        s_h[t] = a;
    }
    __syncthreads();

    // ---------- W2 [512 x 128] ----------
    wait_vm0();
    gemv128(s_h, wbuf, s_part, w, ln);
    wait_lgkm0();
    if (l < DEPTH - 1) wstage16(WqL + w * 16384, lslice, ln);   // issue Wq DMA
    __syncthreads();
    float y = 0.0f;
    if (own) {
        y = b2[l * DIMM + d];
#pragma unroll
        for (int g = 0; g < 8; g++) y += s_part[g * 128 + d];
    }
    __syncthreads();

    // gate2
    const float* Wg2_l = Wg2 + l * 3 * DIMM;
    texpr = own ? (y * Wg2_l[d] + n1 * Wg2_l[DIMM + d] + (y - n1) * Wg2_l[2 * DIMM + d]) : 0.0f;
    float g2 = block_reduce_sum_8w(texpr, s_red);
    g2 = 1.0f / (1.0f + __expf(-g2));
    float n2 = y * g2 + n1 * (1.0f - g2);
    if (own) nodes[bn * DIMM + d] = n2;

    if (l < DEPTH - 1) {
        // LN1 for next layer
        float m1   = block_reduce_sum_8w(own ? n2 : 0.0f, s_red) * (1.0f / 128.0f);
        float df1  = n2 - m1;
        float var1 = block_reduce_sum_8w(own ? df1 * df1 : 0.0f, s_red) * (1.0f / 128.0f);
        if (own) s_xn[d] = df1 * rsqrtf(var1 + 1e-5f) * ln1_g[(l + 1) * DIMM + d]
                         + ln1_b[(l + 1) * DIMM + d];
        __syncthreads();

        // Wq
        wait_vm0();
        gemv512(s_xn, wbuf, s_part, w, ln);
        wait_lgkm0();
        wstage16s(WkvL + (size_t)(w * 16) * 2048, 2048, lslice, ln);   // Wk
        __syncthreads();
        {
            float q = bq[(l + 1) * INNER + t];
#pragma unroll
            for (int g = 0; g < 8; g++) q += s_part[g * 512 + t];
            qb[(size_t)bn * INNER + t] = q;
        }
        __syncthreads();

        // Wk
        wait_vm0();
        gemv512(s_xn, wbuf, s_part, w, ln);
        wait_lgkm0();
        wstage16s(WkvL + (size_t)(w * 16) * 2048 + 1024, 2048, lslice, ln);   // Wv
        __syncthreads();
        {
            float k = bkv[(l + 1) * 2 * INNER + t];
#pragma unroll
            for (int g = 0; g < 8; g++) k += s_part[g * 512 + t];
            hkout[(size_t)bn * INNER + t] = __float2half(k);
        }
        __syncthreads();

        // Wv
        wait_vm0();
        gemv512(s_xn, wbuf, s_part, w, ln);
        __syncthreads();
        {
            float v = bkv[(l + 1) * 2 * INNER + INNER + t];
#pragma unroll
            for (int g = 0; g < 8; g++) v += s_part[g * 512 + t];
            hvout[(size_t)bn * INNER + t] = __float2half(v);
        }
    }
}

__global__ __launch_bounds__(256) void k_final(const float* nodes, const float* Wlin,
                                               const float* blin, float* out) {
    int t = threadIdx.x;
    __shared__ float s_w[DIMM];
    if (t < DIMM) s_w[t] = Wlin[t];
    __syncthreads();
    float s = blin[0];
    const float4* nr = (const float4*)(nodes + t * DIMM);
#pragma unroll 8
    for (int q = 0; q < 32; q++) {
        float4 n = nr[q];
        s += n.x * s_w[4 * q] + n.y * s_w[4 * q + 1] + n.z * s_w[4 * q + 2] + n.w * s_w[4 * q + 3];
    }
#pragma unroll
    for (int off = 32; off > 0; off >>= 1) s += __shfl_xor(s, off, 64);
    __shared__ float sb[4];
    int wave = t >> 6, lane = t & 63;
    if (lane == 0) sb[wave] = s;
    __syncthreads();
    if (t == 0) out[0] = sb[0] + sb[1] + sb[2] + sb[3];
}

extern "C" void kernel_launch(void* const* d_in, const int* in_sizes, int n_in,
                              void* d_out, int out_size, void* d_ws, size_t ws_size,
                              hipStream_t stream) {
    const int*   indices = (const int*)d_in[0];
    const float* coords  = (const float*)d_in[1];
    const int*   bonds   = (const int*)d_in[2];
    const float* noise   = (const float*)d_in[3];
    const float* atom_emb= (const float*)d_in[4];
    const float* ln1_g   = (const float*)d_in[5];
    const float* ln1_b   = (const float*)d_in[6];
    const float* Wq      = (const float*)d_in[7];
    const float* bq      = (const float*)d_in[8];
    const float* Wkv     = (const float*)d_in[9];
    const float* bkv     = (const float*)d_in[10];
    const float* We      = (const float*)d_in[11];
    const float* be      = (const float*)d_in[12];
    const float* Wo      = (const float*)d_in[13];
    const float* bo      = (const float*)d_in[14];
    const float* Wg1     = (const float*)d_in[15];
    const float* ln2_g   = (const float*)d_in[16];
    const float* ln2_b   = (const float*)d_in[17];
    const float* W1      = (const float*)d_in[18];
    const float* b1      = (const float*)d_in[19];
    const float* W2      = (const float*)d_in[20];
    const float* b2      = (const float*)d_in[21];
    const float* Wg2     = (const float*)d_in[22];
    const float* Wlin    = (const float*)d_in[23];
    const float* blin    = (const float*)d_in[24];

    float*  ws    = (float*)d_ws;
    float*  nodes = ws;                         // 32768 f
    float*  qb    = nodes + NNODE * DIMM;       // 131072 f
    __half* hkb   = (__half*)(qb + NNODE * INNER);  // 2 slabs x 131072 halves
    __half* hvb   = hkb + 2 * NNODE * INNER;
    __half* hWq   = hvb + 2 * NNODE * INNER;
    __half* hWkv  = hWq + DEPTH * DIMM * INNER;
    __half* hWo   = hWkv + DEPTH * DIMM * 2 * INNER;
    __half* hW1   = hWo + DEPTH * INNER * DIMM;
    __half* hW2   = hW1 + DEPTH * DIMM * 4 * DIMM;

    k_cvt<<<1152, 512, 0, stream>>>(Wq, Wkv, Wo, W1, W2, hWq, hWkv, hWo, hW1, hW2);
    k_pre<<<NNODE, 512, 0, stream>>>(indices, noise, atom_emb, ln1_g, ln1_b,
                                     hWq, bq, hWkv, bkv, nodes, qb, hkb, hvb);
    for (int l = 0; l < DEPTH; l++) {
        const __half* hkin = hkb + (size_t)(l & 1) * NNODE * INNER;
        const __half* hvin = hvb + (size_t)(l & 1) * NNODE * INNER;
        __half* hkout = hkb + (size_t)((l + 1) & 1) * NNODE * INNER;
        __half* hvout = hvb + (size_t)((l + 1) & 1) * NNODE * INNER;
        k_layer<<<NNODE, 512, 0, stream>>>(l, coords, bonds, We, be,
                                           qb, hkin, hvin, hkout, hvout,
                                           hWo, bo, Wg1, ln2_g, ln2_b, hW1, b1, hW2, b2,
                                           Wg2, ln1_g, ln1_b, hWq, bq, hWkv, bkv, nodes);
    }
    k_final<<<1, 256, 0, stream>>>(nodes, Wlin, blin, (float*)d_out);
}

// Round 15
// 267.033 us; speedup vs baseline: 1.9454x; 1.0555x over previous
//
#include <hip/hip_runtime.h>
#include <hip/hip_fp16.h>
#include <math.h>

#define DEPTH 6
#define HEADS 8
#define BB    2
#define NN    128
#define EE    160
#define NF    127
#define DIMM  128
#define INNER 512
#define NNODE 256

__device__ __forceinline__ void gload16(const void* g, void* l) {
    __builtin_amdgcn_global_load_lds((const __attribute__((address_space(1))) void*)g,
                                     (__attribute__((address_space(3))) void*)l,
                                     16, 0, 0);
}

// wait this wave's outstanding vmem (vmcnt(0); lgkm/exp unconstrained)
__device__ __forceinline__ void wait_vm0() { __builtin_amdgcn_s_waitcnt(0x0f70); }
// drain this wave's LDS ops before slice overwrite
__device__ __forceinline__ void wait_lgkm0() { __builtin_amdgcn_s_waitcnt(0xC07F); }

// Per-wave 16 KB contiguous stage: 16 x (1 KB gload16). ldsslice wave-uniform.
__device__ __forceinline__ void wstage16(const char* gslice, char* ldsslice, int ln) {
#pragma unroll
    for (int i = 0; i < 16; i++)
        gload16(gslice + i * 1024 + ln * 16, ldsslice + i * 1024);
}
// Strided variant: 16 rows of 1 KB, global row stride `rowstride` bytes.
__device__ __forceinline__ void wstage16s(const char* gslice, int rowstride,
                                          char* ldsslice, int ln) {
#pragma unroll
    for (int i = 0; i < 16; i++)
        gload16(gslice + (size_t)i * rowstride + ln * 16, ldsslice + i * 1024);
}

__device__ __forceinline__ void fma8h(float4& a0, float4& a1, float s, float4 raw) {
    const __half2* hp = (const __half2*)&raw;
    float2 p0 = __half22float2(hp[0]), p1 = __half22float2(hp[1]);
    float2 p2 = __half22float2(hp[2]), p3 = __half22float2(hp[3]);
    a0.x += s * p0.x; a0.y += s * p0.y; a0.z += s * p1.x; a0.w += s * p1.y;
    a1.x += s * p2.x; a1.y += s * p2.y; a1.z += s * p3.x; a1.w += s * p3.y;
}

// GEMV unit, C=512 K=128, wave w owns rows [w*16, w*16+16). wbuf = 16 rows x 1KB.
__device__ __forceinline__ void gemv512(const float* act, const float* wbuf,
                                        float* s_part, int w, int ln) {
    float4 a0 = {0,0,0,0}, a1 = {0,0,0,0};
    const float4* w4 = (const float4*)wbuf;
#pragma unroll
    for (int r = 0; r < 16; r++)
        fma8h(a0, a1, act[w * 16 + r], w4[r * 64 + ln]);
    ((float4*)(s_part + w * 512))[ln * 2]     = a0;
    ((float4*)(s_part + w * 512))[ln * 2 + 1] = a1;
}

// GEMV unit, C=128 K=512, wave w owns rows [w*64, w*64+64). wbuf = 64 rows x 256B.
__device__ __forceinline__ void gemv128(const float* act, const float* wbuf,
                                        float* s_part, int w, int ln) {
    float2 acc = {0, 0};
#pragma unroll 8
    for (int r = 0; r < 64; r++) {
        float raw = wbuf[r * 64 + ln];
        __half2 h = *(__half2*)&raw;
        float2 p = __half22float2(h);
        float a = act[w * 64 + r];
        acc.x += a * p.x; acc.y += a * p.y;
    }
    s_part[w * 128 + ln * 2]     = acc.x;
    s_part[w * 128 + ln * 2 + 1] = acc.y;
}

__device__ __forceinline__ float block_reduce_sum_8w(float val, float* sbuf) {
#pragma unroll
    for (int off = 32; off > 0; off >>= 1) val += __shfl_xor(val, off, 64);
    int wave = threadIdx.x >> 6;
    if ((threadIdx.x & 63) == 0) sbuf[wave] = val;
    __syncthreads();
    float r = sbuf[0] + sbuf[1] + sbuf[2] + sbuf[3] + sbuf[4] + sbuf[5] + sbuf[6] + sbuf[7];
    __syncthreads();
    return r;
}

// dual reduce: returns {sum(a), sum(b)} with a single barrier pair.
__device__ __forceinline__ float2 block_reduce_sum2_8w(float a, float b, float* sbuf16) {
#pragma unroll
    for (int off = 32; off > 0; off >>= 1) {
        a += __shfl_xor(a, off, 64);
        b += __shfl_xor(b, off, 64);
    }
    int wave = threadIdx.x >> 6;
    if ((threadIdx.x & 63) == 0) { sbuf16[2 * wave] = a; sbuf16[2 * wave + 1] = b; }
    __syncthreads();
    float ra = 0.0f, rb = 0.0f;
#pragma unroll
    for (int g = 0; g < 8; g++) { ra += sbuf16[2 * g]; rb += sbuf16[2 * g + 1]; }
    __syncthreads();
    float2 r; r.x = ra; r.y = rb;
    return r;
}

// ---------- kernels ----------

__global__ __launch_bounds__(512) void k_cvt(const float* Wq, const float* Wkv,
                                             const float* Wo, const float* W1,
                                             const float* W2,
                                             __half* hWq, __half* hWkv, __half* hWo,
                                             __half* hW1, __half* hW2,
                                             const float* blin, float* out) {
    if (blockIdx.x == 0 && threadIdx.x == 0) out[0] = 256.0f * blin[0];
    int g = blockIdx.x * 512 + threadIdx.x;
    const float4* src; __half* dst; int off;
    if (g < 98304)       { src = (const float4*)Wq;  dst = hWq;  off = g; }
    else if (g < 294912) { src = (const float4*)Wkv; dst = hWkv; off = g - 98304; }
    else if (g < 393216) { src = (const float4*)Wo;  dst = hWo;  off = g - 294912; }
    else if (g < 491520) { src = (const float4*)W1;  dst = hW1;  off = g - 393216; }
    else                 { src = (const float4*)W2;  dst = hW2;  off = g - 491520; }
    float4 v = src[off];
    __half2* d2 = (__half2*)(dst + (size_t)off * 4);
    d2[0] = __floats2half2_rn(v.x, v.y);
    d2[1] = __floats2half2_rn(v.z, v.w);
}

__global__ __launch_bounds__(512, 1) void k_pre(const int* indices, const float* noise,
                                                const float* atom_emb,
                                                const float* ln1_g, const float* ln1_b,
                                                const __half* hWq, const float* bq,
                                                const __half* hWkv, const float* bkv,
                                                float* nodes, float* qb,
                                                __half* hk, __half* hv) {
    int bn = blockIdx.x;
    int t  = threadIdx.x;
    int d  = t & 127;
    bool own = (t < 128);
    int w = t >> 6, ln = t & 63;
    __shared__ float arena[32768];
    __shared__ float s_xn[128];
    __shared__ float s_red[16];
    __shared__ float s_part[4096];
    char*  lslice = (char*)arena + w * 16384;
    float* wbuf   = arena + w * 4096;

    // stage Wq immediately; DMA overlaps gather + LN
    const char* WqL  = (const char*)(hWq + 0);
    const char* WkvL = (const char*)(hWkv + 0);
    wstage16(WqL + w * 16384, lslice, ln);

    float nd = 0.0f;
    if (own) {
        int idx = indices[bn];
        nd = (d < NF) ? atom_emb[idx * NF + d] : noise[0];
        nodes[bn * DIMM + d] = nd;
    }
    float2 ss = block_reduce_sum2_8w(own ? nd : 0.0f, own ? nd * nd : 0.0f, s_red);
    float m   = ss.x * (1.0f / 128.0f);
    float var = ss.y * (1.0f / 128.0f) - m * m;
    if (own) s_xn[d] = (nd - m) * rsqrtf(var + 1e-5f) * ln1_g[d] + ln1_b[d];
    __syncthreads();

    // Wq
    wait_vm0();
    gemv512(s_xn, wbuf, s_part, w, ln);
    wait_lgkm0();
    wstage16s(WkvL + (size_t)(w * 16) * 2048, 2048, lslice, ln);   // Wk
    __syncthreads();
    {
        float q = bq[t];
#pragma unroll
        for (int g = 0; g < 8; g++) q += s_part[g * 512 + t];
        qb[(size_t)bn * INNER + t] = q;
    }
    __syncthreads();

    // Wk
    wait_vm0();
    gemv512(s_xn, wbuf, s_part, w, ln);
    wait_lgkm0();
    wstage16s(WkvL + (size_t)(w * 16) * 2048 + 1024, 2048, lslice, ln);   // Wv
    __syncthreads();
    {
        float k = bkv[t];
#pragma unroll
        for (int g = 0; g < 8; g++) k += s_part[g * 512 + t];
        hk[(size_t)bn * INNER + t] = __float2half(k);
    }
    __syncthreads();

    // Wv
    wait_vm0();
    gemv512(s_xn, wbuf, s_part, w, ln);
    __syncthreads();
    {
        float v = bkv[INNER + t];
#pragma unroll
        for (int g = 0; g < 8; g++) v += s_part[g * 512 + t];
        hv[(size_t)bn * INNER + t] = __float2half(v);
    }
}

__global__ __launch_bounds__(512, 1) void k_layer(int l,
        const float* coords, const int* bonds,
        const float* We, const float* be,
        float* qb, const __half* hkin, const __half* hvin,
        __half* hkout, __half* hvout,
        const __half* hWo, const float* bo, const float* Wg1,
        const float* ln2_g, const float* ln2_b,
        const __half* hW1, const float* b1,
        const __half* hW2, const float* b2,
        const float* Wg2,
        const float* ln1_g, const float* ln1_b,
        const __half* hWq, const float* bq,
        const __half* hWkv, const float* bkv,
        float* nodes, const float* Wlin, float* out) {
    int bn = blockIdx.x;
    int b = bn >> 7, i = bn & 127;
    int t = threadIdx.x;
    int d = t & 127;
    bool own = (t < 128);
    int w = t >> 6, ln = t & 63;

    __shared__ float arena[32768];     // per-wave weight slices (16 KB each)
    __shared__ float scoord[384];
    __shared__ float sedge[384];
    __shared__ int   sadj[128];
    __shared__ float s_l[64];
    __shared__ float s_ao[512];
    __shared__ float s_h[512];
    __shared__ float s_xn[128];
    __shared__ float s_red[16];
    __shared__ float s_part[4096];     // aliased as s_o (8 waves x 512) in attention
    float* s_o = s_part;
    char*  lslice = (char*)arena + w * 16384;
    float* wbuf   = arena + w * 4096;

    const char* WoL  = (const char*)(hWo + (size_t)l * INNER * DIMM);
    const char* W1L  = (const char*)(hW1 + (size_t)l * DIMM * 4 * DIMM);
    const char* W2L  = (const char*)(hW2 + (size_t)l * 4 * DIMM * DIMM);
    const char* WqL  = (const char*)(hWq + (size_t)(l + 1) * DIMM * INNER);
    const char* WkvL = (const char*)(hWkv + (size_t)(l + 1) * DIMM * 2 * INNER);

    // stage Wo immediately; DMA overlaps the whole attention phase
    wstage16(WoL + w * 16384, lslice, ln);

    // ---------- attention: wave w owns j in [w*16, w*16+16); 64 lanes = 512 dims ----------
    // lane ln covers dims ln*8 .. ln*8+7; head h = ln>>3
    const float4* qR4 = (const float4*)(qb + (size_t)bn * INNER);
    const float4* WeR = (const float4*)(We + (size_t)l * 3 * INNER);
    float4 qa  = qR4[ln * 2],        qz  = qR4[ln * 2 + 1];
    float4 w0a = WeR[ln * 2],        w0z = WeR[ln * 2 + 1];
    float4 w1a = WeR[128 + ln * 2],  w1z = WeR[129 + ln * 2];
    float4 w2a = WeR[256 + ln * 2],  w2z = WeR[257 + ln * 2];
    float4 bea = ((const float4*)(be + (size_t)l * INNER))[ln * 2];
    float4 bez = ((const float4*)(be + (size_t)l * INNER))[ln * 2 + 1];
    float res = own ? nodes[bn * DIMM + d] : 0.0f;

    if (t < 3 * NN) scoord[t] = coords[b * 3 * NN + t];
    if (t < NN) sadj[t] = 0;
    __syncthreads();
    if (t < EE) {
        int e0 = bonds[2 * t], e1 = bonds[2 * t + 1];
        if (e0 == i) sadj[e1] = 1;
        if (e1 == i) sadj[e0] = 1;
    }
    __syncthreads();
    if (t < NN) {
        int j = t;
        float msk = sadj[j] ? 1.0f : 0.0f;
        sedge[3 * j + 0] = msk * (scoord[3 * i + 0] - scoord[3 * j + 0]);
        sedge[3 * j + 1] = msk * (scoord[3 * i + 1] - scoord[3 * j + 1]);
        sedge[3 * j + 2] = msk * (scoord[3 * i + 2] - scoord[3 * j + 2]);
    }
    __syncthreads();

    const float4* kR = (const float4*)(hkin + (size_t)b * NN * INNER);   // 8 halves/elt
    const float4* vR = (const float4*)(hvin + (size_t)b * NN * INNER);
    float l_run = 0.0f;
    float4 o0 = {0, 0, 0, 0}, o1 = {0, 0, 0, 0};
    int j0 = w * 16;
#pragma unroll
    for (int base = 0; base < 16; base += 4) {
        float4 kraw[4], vraw[4];
#pragma unroll
        for (int p = 0; p < 4; p++) {
            int j = j0 + base + p;
            kraw[p] = kR[j * 64 + ln];
            vraw[p] = vR[j * 64 + ln];
        }
#pragma unroll
        for (int p = 0; p < 4; p++) {
            int j = j0 + base + p;
            float ex = sedge[3 * j], ey = sedge[3 * j + 1], ez = sedge[3 * j + 2];
            float4 e0, e1;
            e0.x = bea.x + ex * w0a.x + ey * w1a.x + ez * w2a.x;
            e0.y = bea.y + ex * w0a.y + ey * w1a.y + ez * w2a.y;
            e0.z = bea.z + ex * w0a.z + ey * w1a.z + ez * w2a.z;
            e0.w = bea.w + ex * w0a.w + ey * w1a.w + ez * w2a.w;
            e1.x = bez.x + ex * w0z.x + ey * w1z.x + ez * w2z.x;
            e1.y = bez.y + ex * w0z.y + ey * w1z.y + ez * w2z.y;
            e1.z = bez.z + ex * w0z.z + ey * w1z.z + ez * w2z.z;
            e1.w = bez.w + ex * w0z.w + ey * w1z.w + ez * w2z.w;
            const __half2* kh = (const __half2*)&kraw[p];
            float2 k0 = __half22float2(kh[0]), k1 = __half22float2(kh[1]);
            float2 k2 = __half22float2(kh[2]), k3 = __half22float2(kh[3]);
            float s = qa.x * (k0.x + e0.x) + qa.y * (k0.y + e0.y)
                    + qa.z * (k1.x + e0.z) + qa.w * (k1.y + e0.w)
                    + qz.x * (k2.x + e1.x) + qz.y * (k2.y + e1.y)
                    + qz.z * (k3.x + e1.z) + qz.w * (k3.y + e1.w);
            s += __shfl_xor(s, 1, 64);
            s += __shfl_xor(s, 2, 64);
            s += __shfl_xor(s, 4, 64);
            float pp = __expf(s * 0.125f);
            const __half2* vh = (const __half2*)&vraw[p];
            float2 v0 = __half22float2(vh[0]), v1 = __half22float2(vh[1]);
            float2 v2 = __half22float2(vh[2]), v3 = __half22float2(vh[3]);
            l_run += pp;
            o0.x += pp * (v0.x + e0.x); o0.y += pp * (v0.y + e0.y);
            o0.z += pp * (v1.x + e0.z); o0.w += pp * (v1.y + e0.w);
            o1.x += pp * (v2.x + e1.x); o1.y += pp * (v2.y + e1.y);
            o1.z += pp * (v3.x + e1.z); o1.w += pp * (v3.y + e1.w);
        }
    }
    ((float4*)(s_o + w * 512))[ln * 2]     = o0;
    ((float4*)(s_o + w * 512))[ln * 2 + 1] = o1;
    if ((ln & 7) == 0) s_l[w * 8 + (ln >> 3)] = l_run;
    __syncthreads();
    {
        float o = 0.0f;
#pragma unroll
        for (int g = 0; g < 8; g++) o += s_o[g * 512 + t];
        int h = t >> 6;
        float lsum = 0.0f;
#pragma unroll
        for (int g = 0; g < 8; g++) lsum += s_l[g * 8 + h];
        s_ao[t] = o / lsum;
    }
    __syncthreads();

    // ---------- Wo [512 x 128] ----------
    wait_vm0();
    gemv128(s_ao, wbuf, s_part, w, ln);
    wait_lgkm0();
    wstage16(W1L + w * 16384, lslice, ln);   // W1 DMA flies during gate1/LN2
    __syncthreads();
    float x = 0.0f;
    if (own) {
        x = bo[l * DIMM + d];
#pragma unroll
        for (int g = 0; g < 8; g++) x += s_part[g * 128 + d];
    }
    __syncthreads();

    // gate1
    const float* Wg1_l = Wg1 + l * 3 * DIMM;
    float texpr = own ? (x * Wg1_l[d] + res * Wg1_l[DIMM + d] + (x - res) * Wg1_l[2 * DIMM + d]) : 0.0f;
    float g1 = block_reduce_sum_8w(texpr, s_red);
    g1 = 1.0f / (1.0f + __expf(-g1));
    float n1 = x * g1 + res * (1.0f - g1);

    // LN2 (fused mean/var)
    float2 ss = block_reduce_sum2_8w(own ? n1 : 0.0f, own ? n1 * n1 : 0.0f, s_red);
    float m   = ss.x * (1.0f / 128.0f);
    float var = ss.y * (1.0f / 128.0f) - m * m;
    if (own) s_xn[d] = (n1 - m) * rsqrtf(var + 1e-5f) * ln2_g[l * DIMM + d] + ln2_b[l * DIMM + d];
    __syncthreads();

    // ---------- W1 [128 x 512] + gelu ----------
    wait_vm0();
    gemv512(s_xn, wbuf, s_part, w, ln);
    wait_lgkm0();
    wstage16(W2L + w * 16384, lslice, ln);   // W2 DMA flies during gelu combine
    __syncthreads();
    {
        float a = b1[l * 4 * DIMM + t];
#pragma unroll
        for (int g = 0; g < 8; g++) a += s_part[g * 512 + t];
        a = 0.5f * a * (1.0f + erff(a * 0.70710678f));
        s_h[t] = a;
    }
    __syncthreads();

    // ---------- W2 [512 x 128] ----------
    wait_vm0();
    gemv128(s_h, wbuf, s_part, w, ln);
    wait_lgkm0();
    if (l < DEPTH - 1) wstage16(WqL + w * 16384, lslice, ln);   // Wq DMA
    __syncthreads();
    float y = 0.0f;
    if (own) {
        y = b2[l * DIMM + d];
#pragma unroll
        for (int g = 0; g < 8; g++) y += s_part[g * 128 + d];
    }
    __syncthreads();

    // gate2
    const float* Wg2_l = Wg2 + l * 3 * DIMM;
    texpr = own ? (y * Wg2_l[d] + n1 * Wg2_l[DIMM + d] + (y - n1) * Wg2_l[2 * DIMM + d]) : 0.0f;
    float g2 = block_reduce_sum_8w(texpr, s_red);
    g2 = 1.0f / (1.0f + __expf(-g2));
    float n2 = y * g2 + n1 * (1.0f - g2);
    if (own) nodes[bn * DIMM + d] = n2;

    if (l < DEPTH - 1) {
        // LN1 for next layer (fused mean/var)
        float2 s1 = block_reduce_sum2_8w(own ? n2 : 0.0f, own ? n2 * n2 : 0.0f, s_red);
        float m1   = s1.x * (1.0f / 128.0f);
        float var1 = s1.y * (1.0f / 128.0f) - m1 * m1;
        if (own) s_xn[d] = (n2 - m1) * rsqrtf(var1 + 1e-5f) * ln1_g[(l + 1) * DIMM + d]
                         + ln1_b[(l + 1) * DIMM + d];
        __syncthreads();

        // Wq
        wait_vm0();
        gemv512(s_xn, wbuf, s_part, w, ln);
        wait_lgkm0();
        wstage16s(WkvL + (size_t)(w * 16) * 2048, 2048, lslice, ln);   // Wk
        __syncthreads();
        {
            float q = bq[(l + 1) * INNER + t];
#pragma unroll
            for (int g = 0; g < 8; g++) q += s_part[g * 512 + t];
            qb[(size_t)bn * INNER + t] = q;
        }
        __syncthreads();

        // Wk
        wait_vm0();
        gemv512(s_xn, wbuf, s_part, w, ln);
        wait_lgkm0();
        wstage16s(WkvL + (size_t)(w * 16) * 2048 + 1024, 2048, lslice, ln);   // Wv
        __syncthreads();
        {
            float k = bkv[(l + 1) * 2 * INNER + t];
#pragma unroll
            for (int g = 0; g < 8; g++) k += s_part[g * 512 + t];
            hkout[(size_t)bn * INNER + t] = __float2half(k);
        }
        __syncthreads();

        // Wv
        wait_vm0();
        gemv512(s_xn, wbuf, s_part, w, ln);
        __syncthreads();
        {
            float v = bkv[(l + 1) * 2 * INNER + INNER + t];
#pragma unroll
            for (int g = 0; g < 8; g++) v += s_part[g * 512 + t];
            hvout[(size_t)bn * INNER + t] = __float2half(v);
        }
    } else {
        // final: this node's contribution to sum(nodes @ Wlin) (out pre-init in k_cvt)
        float contrib = own ? n2 * Wlin[d] : 0.0f;
        float tot = block_reduce_sum_8w(contrib, s_red);
        if (t == 0) atomicAdd(out, tot);
    }
}

extern "C" void kernel_launch(void* const* d_in, const int* in_sizes, int n_in,
                              void* d_out, int out_size, void* d_ws, size_t ws_size,
                              hipStream_t stream) {
    const int*   indices = (const int*)d_in[0];
    const float* coords  = (const float*)d_in[1];
    const int*   bonds   = (const int*)d_in[2];
    const float* noise   = (const float*)d_in[3];
    const float* atom_emb= (const float*)d_in[4];
    const float* ln1_g   = (const float*)d_in[5];
    const float* ln1_b   = (const float*)d_in[6];
    const float* Wq      = (const float*)d_in[7];
    const float* bq      = (const float*)d_in[8];
    const float* Wkv     = (const float*)d_in[9];
    const float* bkv     = (const float*)d_in[10];
    const float* We      = (const float*)d_in[11];
    const float* be      = (const float*)d_in[12];
    const float* Wo      = (const float*)d_in[13];
    const float* bo      = (const float*)d_in[14];
    const float* Wg1     = (const float*)d_in[15];
    const float* ln2_g   = (const float*)d_in[16];
    const float* ln2_b   = (const float*)d_in[17];
    const float* W1      = (const float*)d_in[18];
    const float* b1      = (const float*)d_in[19];
    const float* W2      = (const float*)d_in[20];
    const float* b2      = (const float*)d_in[21];
    const float* Wg2     = (const float*)d_in[22];
    const float* Wlin    = (const float*)d_in[23];
    const float* blin    = (const float*)d_in[24];

    float*  ws    = (float*)d_ws;
    float*  nodes = ws;                         // 32768 f
    float*  qb    = nodes + NNODE * DIMM;       // 131072 f
    __half* hkb   = (__half*)(qb + NNODE * INNER);  // 2 slabs x 131072 halves
    __half* hvb   = hkb + 2 * NNODE * INNER;
    __half* hWq   = hvb + 2 * NNODE * INNER;
    __half* hWkv  = hWq + DEPTH * DIMM * INNER;
    __half* hWo   = hWkv + DEPTH * DIMM * 2 * INNER;
    __half* hW1   = hWo + DEPTH * INNER * DIMM;
    __half* hW2   = hW1 + DEPTH * DIMM * 4 * DIMM;

    k_cvt<<<1152, 512, 0, stream>>>(Wq, Wkv, Wo, W1, W2, hWq, hWkv, hWo, hW1, hW2,
                                    blin, (float*)d_out);
    k_pre<<<NNODE, 512, 0, stream>>>(indices, noise, atom_emb, ln1_g, ln1_b,
                                     hWq, bq, hWkv, bkv, nodes, qb, hkb, hvb);
    for (int l = 0; l < DEPTH; l++) {
        const __half* hkin = hkb + (size_t)(l & 1) * NNODE * INNER;
        const __half* hvin = hvb + (size_t)(l & 1) * NNODE * INNER;
        __half* hkout = hkb + (size_t)((l + 1) & 1) * NNODE * INNER;
        __half* hvout = hvb + (size_t)((l + 1) & 1) * NNODE * INNER;
        k_layer<<<NNODE, 512, 0, stream>>>(l, coords, bonds, We, be,
                                           qb, hkin, hvin, hkout, hvout,
                                           hWo, bo, Wg1, ln2_g, ln2_b, hW1, b1, hW2, b2,
                                           Wg2, ln1_g, ln1_b, hWq, bq, hWkv, bkv,
                                           nodes, Wlin, (float*)d_out);
    }
}